// Round 11
// baseline (591.913 us; speedup 1.0000x reference)
//
#include <hip/hip_runtime.h>

typedef __attribute__((ext_vector_type(8))) _Float16 f16x8;
typedef __attribute__((ext_vector_type(4))) _Float16 f16x4;
typedef __attribute__((ext_vector_type(4))) float f32x4;

#define PWS 72   // LDS tile pitch in halfs: 144B rows, 16B-aligned chunks

__device__ __forceinline__ float silu_f(float v) {
    return v * (1.0f / (1.0f + __expf(-v)));
}

// ---------------------------------------------------------------------------
// Weight pre-conversion: fp32 [K][64] -> f16 in B-fragment order.
// ---------------------------------------------------------------------------
struct WDesc { const float* W; _Float16* out; int K; };
struct WPack { WDesc d[8]; };

__global__ __launch_bounds__(256) void conv_weights(WPack p) {
    WDesc wd = p.d[blockIdx.y];
    int total = wd.K * 64;
    int i = blockIdx.x * 256 + threadIdx.x;
    if (i >= total) return;
    int j  = i & 7;
    int l  = (i >> 3) & 63;
    int tn = i >> 9;                 // t*4 + nf
    int t  = tn >> 2, nf = tn & 3;
    int k  = t * 32 + (l >> 4) * 8 + j;
    int c  = nf * 16 + (l & 15);
    wd.out[i] = (_Float16)wd.W[k * 64 + c];   // RNE
}

// ---------------------------------------------------------------------------
// CSR build: histogram -> single-block scan -> scatter (emits sorted eid,
// src, dst arrays). cursor aliases counts.
// ---------------------------------------------------------------------------
__global__ __launch_bounds__(256) void hist_kernel(const int* __restrict__ dst,
                                                   int* __restrict__ counts, int E) {
    int e = blockIdx.x * 256 + threadIdx.x;
    if (e < E) atomicAdd(&counts[dst[e]], 1);
}

__global__ __launch_bounds__(1024) void scan_kernel(int* __restrict__ counts,
                                                    int* __restrict__ row_ptr,
                                                    int N, int E) {
    __shared__ int part[1024];
    int t = threadIdx.x;
    int per = (N + 1023) >> 10;
    int s = t * per, en = min(s + per, N);
    int sum = 0;
    for (int i = s; i < en; ++i) sum += counts[i];
    part[t] = sum;
    __syncthreads();
    for (int off = 1; off < 1024; off <<= 1) {
        int v = (t >= off) ? part[t - off] : 0;
        __syncthreads();
        part[t] += v;
        __syncthreads();
    }
    int run = (t == 0) ? 0 : part[t - 1];
    for (int i = s; i < en; ++i) {
        int c = counts[i];
        row_ptr[i] = run;
        counts[i] = run;        // becomes the scatter cursor
        run += c;
    }
    if (t == 1023) row_ptr[N] = E;
}

__global__ __launch_bounds__(256) void scatter_kernel(
    const int* __restrict__ src, const int* __restrict__ dst,
    int* __restrict__ cursor,
    int* __restrict__ csr_eid, int* __restrict__ srcS, int* __restrict__ dstS,
    int E) {
    int e = blockIdx.x * 256 + threadIdx.x;
    if (e < E) {
        int d = dst[e];
        int pos = atomicAdd(&cursor[d], 1);
        csr_eid[pos] = e;
        srcS[pos] = src[e];
        dstS[pos] = d;
    }
}

// ---------------------------------------------------------------------------
// Sorted edge kernel: 4 independent waves/block, wave owns 16 sorted
// positions. No atomics. IN16: read ea from sorted f16 ea_mid (sequential);
// else gather fp32 ea0 via csr_eid. Always writes sorted f16 ea_mid (in-place
// safe: each position read+written only by its owning wave, reads precede
// writes). FINAL: additionally scatter fp32 result to ea_out[eid].
// ---------------------------------------------------------------------------
template <bool IN16, bool FINAL>
__global__ __launch_bounds__(256, 8) void gnn_edge_sorted(
    const float* __restrict__ x,
    const float* __restrict__ ea0,
    _Float16* __restrict__ ea_mid,
    float* __restrict__ ea_out,
    const int* __restrict__ csr_eid,
    const int* __restrict__ srcS,
    const int* __restrict__ dstS,
    const _Float16* __restrict__ w1f,
    const float* __restrict__ b1,
    const _Float16* __restrict__ w2f,
    const float* __restrict__ b2,
    int E)
{
    __shared__ __align__(16) _Float16 sA[64][PWS];

    const int t    = threadIdx.x;
    const int lane = t & 63;
    const int w    = t >> 6;
    const int col  = lane & 15;
    const int g    = lane >> 4;
    const int ko   = g * 8;
    const long base = (long)blockIdx.x * 64;

    // this lane's own position -> eid for the FINAL scatter epilogue
    long p0 = base + w * 16 + col;
    if (p0 >= E) p0 = E - 1;
    int ei0 = 0;
    if constexpr (FINAL) ei0 = csr_eid[p0];

    // ---- upfront loads: rows it*4+g of the wave tile, cols col*4..+4 ----
    f16x4  ea16v[4];
    float4 ea4[4];
    float4 sx4[4], dx4[4];
#pragma unroll
    for (int it = 0; it < 4; ++it) {
        long p = base + w * 16 + it * 4 + g;
        if (p >= E) p = E - 1;
        int ss = srcS[p];
        int ds = dstS[p];
        if constexpr (IN16) {
            ea16v[it] = *(const f16x4*)(ea_mid + p * 64 + col * 4);
        } else {
            int eid = csr_eid[p];
            ea4[it] = *(const float4*)(ea0 + (long)eid * 64 + col * 4);
        }
        sx4[it] = *(const float4*)(x + (long)ss * 64 + col * 4);
        dx4[it] = *(const float4*)(x + (long)ds * 64 + col * 4);
    }

    f32x4 acc[4];
#pragma unroll
    for (int nf = 0; nf < 4; ++nf) {
        float bv = b1[nf * 16 + col];
        acc[nf] = (f32x4){bv, bv, bv, bv};
    }

    const int arow = w * 16 + col;

#define MFMA_L1(s3)                                                             \
    _Pragma("unroll")                                                           \
    for (int tt = 0; tt < 2; ++tt) {                                            \
        int k0 = tt * 32 + ko;                                                  \
        f16x8 af = *(const f16x8*)&sA[arow][k0];                                \
        int tg = (s3) * 2 + tt;                                                 \
        _Pragma("unroll")                                                       \
        for (int nf = 0; nf < 4; ++nf) {                                        \
            f16x8 bf = *(const f16x8*)(w1f + (size_t)((tg*4+nf)*64+lane)*8);    \
            acc[nf] = __builtin_amdgcn_mfma_f32_16x16x32_f16(af, bf, acc[nf], 0, 0, 0); \
        }                                                                       \
    }

    // ---- segment 0: edge_attr (k 0..63) ----
#pragma unroll
    for (int it = 0; it < 4; ++it) {
        int rg = w * 16 + it * 4 + g;
        f16x4 hv;
        if constexpr (IN16) {
            hv = ea16v[it];
        } else {
            hv[0] = (_Float16)ea4[it].x; hv[1] = (_Float16)ea4[it].y;
            hv[2] = (_Float16)ea4[it].z; hv[3] = (_Float16)ea4[it].w;
        }
        *(f16x4*)&sA[rg][col * 4] = hv;
    }
    MFMA_L1(0)

    // ---- segment 1: x[src] (k 64..127) ----
#pragma unroll
    for (int it = 0; it < 4; ++it) {
        int rg = w * 16 + it * 4 + g;
        f16x4 hv;
        hv[0] = (_Float16)sx4[it].x; hv[1] = (_Float16)sx4[it].y;
        hv[2] = (_Float16)sx4[it].z; hv[3] = (_Float16)sx4[it].w;
        *(f16x4*)&sA[rg][col * 4] = hv;
    }
    MFMA_L1(1)

    // ---- segment 2: x[dst] (k 128..191) ----
#pragma unroll
    for (int it = 0; it < 4; ++it) {
        int rg = w * 16 + it * 4 + g;
        f16x4 hv;
        hv[0] = (_Float16)dx4[it].x; hv[1] = (_Float16)dx4[it].y;
        hv[2] = (_Float16)dx4[it].z; hv[3] = (_Float16)dx4[it].w;
        *(f16x4*)&sA[rg][col * 4] = hv;
    }
    MFMA_L1(2)
#undef MFMA_L1

    // ---- silu -> h staged into the wave's own 16 LDS rows (C-frag layout) ----
#pragma unroll
    for (int nf = 0; nf < 4; ++nf)
#pragma unroll
        for (int rg = 0; rg < 4; ++rg) {
            int row = w * 16 + g * 4 + rg;
            sA[row][nf * 16 + col] = (_Float16)silu_f(acc[nf][rg]);
        }

    // ---- layer-2 GEMM (K=64) ----
    f32x4 out[4];
#pragma unroll
    for (int nf = 0; nf < 4; ++nf) {
        float bv = b2[nf * 16 + col];
        out[nf] = (f32x4){bv, bv, bv, bv};
    }
#pragma unroll
    for (int tt = 0; tt < 2; ++tt) {
        int k0 = tt * 32 + ko;
        f16x8 af = *(const f16x8*)&sA[arow][k0];
#pragma unroll
        for (int nf = 0; nf < 4; ++nf) {
            f16x8 bf = *(const f16x8*)(w2f + (size_t)((tt * 4 + nf) * 64 + lane) * 8);
            out[nf] = __builtin_amdgcn_mfma_f32_16x16x32_f16(af, bf, out[nf], 0, 0, 0);
        }
    }

    // ---- epilogue: sequential f16 ea_mid write (+ FINAL fp32 scatter) ----
    const int rbase = w * 16 + g * 4;
#pragma unroll
    for (int rg = 0; rg < 4; ++rg) {
        long p = base + rbase + rg;
        if (p < E) {
#pragma unroll
            for (int nf = 0; nf < 4; ++nf)
                ea_mid[p * 64 + nf * 16 + col] = (_Float16)out[nf][rg];
            if constexpr (FINAL) {
                int eid = __shfl(ei0, g * 4 + rg);
                float* op = ea_out + (long)eid * 64;
#pragma unroll
                for (int nf = 0; nf < 4; ++nf)
                    op[nf * 16 + col] = out[nf][rg];
            }
        }
    }
}

// ---------------------------------------------------------------------------
// Segment-sum aggregation: 16 nodes/block, 16 lanes per node. Sequential f16
// reads over the node's sorted segment, fp32 accumulate, one float4 write.
// Writes every node (degree-0 -> zeros) => no agg memset needed.
// ---------------------------------------------------------------------------
__global__ __launch_bounds__(256) void agg_seg(
    const _Float16* __restrict__ ea_mid,
    const int* __restrict__ row_ptr,
    float* __restrict__ agg, int N)
{
    int t = threadIdx.x;
    long n = (long)blockIdx.x * 16 + (t >> 4);
    int q = t & 15;
    if (n >= N) return;
    int pe0 = row_ptr[n], pe1 = row_ptr[n + 1];
    float a0 = 0.f, a1 = 0.f, a2 = 0.f, a3 = 0.f;
    for (int p = pe0; p < pe1; ++p) {
        f16x4 v = *(const f16x4*)(ea_mid + (long)p * 64 + q * 4);
        a0 += (float)v[0]; a1 += (float)v[1];
        a2 += (float)v[2]; a3 += (float)v[3];
    }
    *(float4*)(agg + n * 64 + q * 4) = make_float4(a0, a1, a2, a3);
}

// ---------------------------------------------------------------------------
// Fallback unsorted edge kernel (R10 path, used only if workspace too small).
// ---------------------------------------------------------------------------
template <bool IN16, bool OUT16>
__global__ __launch_bounds__(256, 8) void gnn_edge_mfma(
    const float* __restrict__ x,
    const float* __restrict__ ea_in,
    const _Float16* __restrict__ ea_in16,
    float* __restrict__ ea_out,
    _Float16* __restrict__ ea_out16,
    const int* __restrict__ src_idx,
    const int* __restrict__ dst_idx,
    const _Float16* __restrict__ w1f,
    const float* __restrict__ b1,
    const _Float16* __restrict__ w2f,
    const float* __restrict__ b2,
    float* __restrict__ agg,
    int E)
{
    __shared__ __align__(16) _Float16 sA[64][PWS];

    const int t    = threadIdx.x;
    const int lane = t & 63;
    const int w    = t >> 6;
    const int col  = lane & 15;
    const int g    = lane >> 4;
    const int ko   = g * 8;
    const long base = (long)blockIdx.x * 64;

    long er0 = base + w * 16 + col;
    if (er0 >= E) er0 = E - 1;
    const int di = dst_idx[er0];

    f16x4  ea16v[4];
    float4 ea4[4];
    float4 sx4[4], dx4[4];
#pragma unroll
    for (int it = 0; it < 4; ++it) {
        long er = base + w * 16 + it * 4 + g;
        if (er >= E) er = E - 1;
        if constexpr (IN16) ea16v[it] = *(const f16x4*)(ea_in16 + er * 64 + col * 4);
        else                ea4[it]   = *(const float4*)(ea_in   + er * 64 + col * 4);
        sx4[it] = *(const float4*)(x + (long)src_idx[er] * 64 + col * 4);
        dx4[it] = *(const float4*)(x + (long)dst_idx[er] * 64 + col * 4);
    }

    f32x4 acc[4];
#pragma unroll
    for (int nf = 0; nf < 4; ++nf) {
        float bv = b1[nf * 16 + col];
        acc[nf] = (f32x4){bv, bv, bv, bv};
    }
    const int arow = w * 16 + col;

#define MFMA_L1(s3)                                                             \
    _Pragma("unroll")                                                           \
    for (int tt = 0; tt < 2; ++tt) {                                            \
        int k0 = tt * 32 + ko;                                                  \
        f16x8 af = *(const f16x8*)&sA[arow][k0];                                \
        int tg = (s3) * 2 + tt;                                                 \
        _Pragma("unroll")                                                       \
        for (int nf = 0; nf < 4; ++nf) {                                        \
            f16x8 bf = *(const f16x8*)(w1f + (size_t)((tg*4+nf)*64+lane)*8);    \
            acc[nf] = __builtin_amdgcn_mfma_f32_16x16x32_f16(af, bf, acc[nf], 0, 0, 0); \
        }                                                                       \
    }

#pragma unroll
    for (int it = 0; it < 4; ++it) {
        int rg = w * 16 + it * 4 + g;
        f16x4 hv;
        if constexpr (IN16) {
            hv = ea16v[it];
        } else {
            hv[0] = (_Float16)ea4[it].x; hv[1] = (_Float16)ea4[it].y;
            hv[2] = (_Float16)ea4[it].z; hv[3] = (_Float16)ea4[it].w;
        }
        *(f16x4*)&sA[rg][col * 4] = hv;
    }
    MFMA_L1(0)
#pragma unroll
    for (int it = 0; it < 4; ++it) {
        int rg = w * 16 + it * 4 + g;
        f16x4 hv;
        hv[0] = (_Float16)sx4[it].x; hv[1] = (_Float16)sx4[it].y;
        hv[2] = (_Float16)sx4[it].z; hv[3] = (_Float16)sx4[it].w;
        *(f16x4*)&sA[rg][col * 4] = hv;
    }
    MFMA_L1(1)
#pragma unroll
    for (int it = 0; it < 4; ++it) {
        int rg = w * 16 + it * 4 + g;
        f16x4 hv;
        hv[0] = (_Float16)dx4[it].x; hv[1] = (_Float16)dx4[it].y;
        hv[2] = (_Float16)dx4[it].z; hv[3] = (_Float16)dx4[it].w;
        *(f16x4*)&sA[rg][col * 4] = hv;
    }
    MFMA_L1(2)
#undef MFMA_L1

#pragma unroll
    for (int nf = 0; nf < 4; ++nf)
#pragma unroll
        for (int rg = 0; rg < 4; ++rg) {
            int row = w * 16 + g * 4 + rg;
            sA[row][nf * 16 + col] = (_Float16)silu_f(acc[nf][rg]);
        }

    f32x4 out[4];
#pragma unroll
    for (int nf = 0; nf < 4; ++nf) {
        float bv = b2[nf * 16 + col];
        out[nf] = (f32x4){bv, bv, bv, bv};
    }
#pragma unroll
    for (int tt = 0; tt < 2; ++tt) {
        int k0 = tt * 32 + ko;
        f16x8 af = *(const f16x8*)&sA[arow][k0];
#pragma unroll
        for (int nf = 0; nf < 4; ++nf) {
            f16x8 bf = *(const f16x8*)(w2f + (size_t)((tt * 4 + nf) * 64 + lane) * 8);
            out[nf] = __builtin_amdgcn_mfma_f32_16x16x32_f16(af, bf, out[nf], 0, 0, 0);
        }
    }

    const int rbase = w * 16 + g * 4;
#pragma unroll
    for (int rg = 0; rg < 4; ++rg) {
        long row = base + rbase + rg;
        if (row < E) {
            int drow = __shfl(di, g * 4 + rg);
            float* ap = agg + (long)drow * 64;
#pragma unroll
            for (int nf = 0; nf < 4; ++nf) {
                if constexpr (OUT16)
                    ea_out16[row * 64 + nf * 16 + col] = (_Float16)out[nf][rg];
                else
                    ea_out[row * 64 + nf * 16 + col] = out[nf][rg];
                atomicAdd(&ap[nf * 16 + col], out[nf][rg]);
            }
        }
    }
}

// ---------------------------------------------------------------------------
// Node kernel (unchanged).
// ---------------------------------------------------------------------------
__global__ __launch_bounds__(256, 8) void gnn_node_mfma(
    const float* __restrict__ x_in,
    const float* __restrict__ aggp,
    float* __restrict__ x_out,
    const _Float16* __restrict__ w1f,
    const float* __restrict__ b1,
    const _Float16* __restrict__ w2f,
    const float* __restrict__ b2, int N)
{
    __shared__ __align__(16) _Float16 sA[64][PWS];

    const int t    = threadIdx.x;
    const int lane = t & 63;
    const int w    = t >> 6;
    const int col  = lane & 15;
    const int g    = lane >> 4;
    const int ko   = g * 8;
    const long base = (long)blockIdx.x * 64;

    long nr = base + w * 16 + col;
    if (nr >= N) nr = N - 1;
    const float* px = x_in + nr * 64 + ko;
    const float* pa = aggp + nr * 64 + ko;

    float4 v0 = *(const float4*)(px);
    float4 v1 = *(const float4*)(px + 4);
    float4 v2 = *(const float4*)(px + 32);
    float4 v3 = *(const float4*)(px + 36);
    float4 v4 = *(const float4*)(pa);
    float4 v5 = *(const float4*)(pa + 4);
    float4 v6 = *(const float4*)(pa + 32);
    float4 v7 = *(const float4*)(pa + 36);

    f32x4 acc[4];
#pragma unroll
    for (int nf = 0; nf < 4; ++nf) {
        float bv = b1[nf * 16 + col];
        acc[nf] = (f32x4){bv, bv, bv, bv};
    }

#define QTR(m, A, B)                                                            \
    {                                                                           \
        f16x8 af;                                                               \
        af[0] = (_Float16)A.x; af[1] = (_Float16)A.y;                           \
        af[2] = (_Float16)A.z; af[3] = (_Float16)A.w;                           \
        af[4] = (_Float16)B.x; af[5] = (_Float16)B.y;                           \
        af[6] = (_Float16)B.z; af[7] = (_Float16)B.w;                           \
        _Pragma("unroll")                                                       \
        for (int nf = 0; nf < 4; ++nf) {                                        \
            f16x8 bf = *(const f16x8*)(w1f + (size_t)(((m)*4+nf)*64+lane)*8);   \
            acc[nf] = __builtin_amdgcn_mfma_f32_16x16x32_f16(af, bf, acc[nf], 0, 0, 0); \
        }                                                                       \
    }
    QTR(0, v0, v1)  QTR(1, v2, v3)   // x    (k 0..63)
    QTR(2, v4, v5)  QTR(3, v6, v7)   // agg  (k 64..127)
#undef QTR

#pragma unroll
    for (int nf = 0; nf < 4; ++nf)
#pragma unroll
        for (int rg = 0; rg < 4; ++rg) {
            int row = w * 16 + g * 4 + rg;
            sA[row][nf * 16 + col] = (_Float16)silu_f(acc[nf][rg]);
        }

    f32x4 out[4];
#pragma unroll
    for (int nf = 0; nf < 4; ++nf) {
        float bv = b2[nf * 16 + col];
        out[nf] = (f32x4){bv, bv, bv, bv};
    }
    const int arow = w * 16 + col;
#pragma unroll
    for (int tt = 0; tt < 2; ++tt) {
        int k0 = tt * 32 + ko;
        f16x8 af = *(const f16x8*)&sA[arow][k0];
#pragma unroll
        for (int nf = 0; nf < 4; ++nf) {
            f16x8 bf = *(const f16x8*)(w2f + (size_t)((tt * 4 + nf) * 64 + lane) * 8);
            out[nf] = __builtin_amdgcn_mfma_f32_16x16x32_f16(af, bf, out[nf], 0, 0, 0);
        }
    }

    const int rbase = w * 16 + g * 4;
#pragma unroll
    for (int rg = 0; rg < 4; ++rg) {
        long row = base + rbase + rg;
        if (row < N) {
            float* op = x_out + row * 64;
#pragma unroll
            for (int nf = 0; nf < 4; ++nf)
                op[nf * 16 + col] = out[nf][rg];
        }
    }
}

extern "C" void kernel_launch(void* const* d_in, const int* in_sizes, int n_in,
                              void* d_out, int out_size, void* d_ws, size_t ws_size,
                              hipStream_t stream) {
    const int H = 64;
    const int N = in_sizes[0] / H;   // 50000
    const int E = in_sizes[1] / H;   // 800000

    const float* x0  = (const float*)d_in[0];
    const float* ea0 = (const float*)d_in[1];
    const int*   ei  = (const int*)d_in[2];
    const float* ew1 = (const float*)d_in[3];
    const float* eb1 = (const float*)d_in[4];
    const float* ew2 = (const float*)d_in[5];
    const float* eb2 = (const float*)d_in[6];
    const float* nw1 = (const float*)d_in[7];
    const float* nb1 = (const float*)d_in[8];
    const float* nw2 = (const float*)d_in[9];
    const float* nb2 = (const float*)d_in[10];

    float* outX = (float*)d_out;                 // [N, H]
    float* outE = outX + (size_t)N * H;          // [E, H]

    // workspace carve: agg | weights | ea_mid f16 | csr ints
    const size_t aggBytes = (size_t)N * H * sizeof(float);
    const size_t wElems   = 2 * ((size_t)(192 + 64 + 128 + 64) * 64);
    const size_t eaHBytes = (size_t)E * H * sizeof(_Float16);

    float* agg      = (float*)d_ws;
    _Float16* wbase = (_Float16*)((char*)d_ws + aggBytes);
    char* eaH_raw   = (char*)(wbase + wElems);
    eaH_raw = (char*)(((uintptr_t)eaH_raw + 15) & ~(uintptr_t)15);
    _Float16* eaH   = (_Float16*)eaH_raw;
    int* counts     = (int*)(((uintptr_t)((char*)eaH + eaHBytes) + 15) & ~(uintptr_t)15);
    int* row_ptr    = counts + N;
    int* csr_eid    = row_ptr + N + 1;
    int* srcS       = csr_eid + E;
    int* dstS       = srcS + E;

    const bool sortedOK = ((char*)(dstS + E)) <= ((char*)d_ws + ws_size);
    const bool f16OK    = ((char*)eaH + eaHBytes) <= ((char*)d_ws + ws_size);

    const int* srcI = ei;
    const int* dstI = ei + E;

    WPack pack;
    size_t off = 0;
    _Float16* EW1[2]; _Float16* EW2[2]; _Float16* NW1[2]; _Float16* NW2[2];
    for (int l = 0; l < 2; ++l) {
        EW1[l] = wbase + off; off += 192 * 64;
        EW2[l] = wbase + off; off += 64 * 64;
        NW1[l] = wbase + off; off += 128 * 64;
        NW2[l] = wbase + off; off += 64 * 64;
        pack.d[l * 4 + 0] = {ew1 + (size_t)l * 192 * 64, EW1[l], 192};
        pack.d[l * 4 + 1] = {ew2 + (size_t)l * 64 * 64,  EW2[l], 64};
        pack.d[l * 4 + 2] = {nw1 + (size_t)l * 128 * 64, NW1[l], 128};
        pack.d[l * 4 + 3] = {nw2 + (size_t)l * 64 * 64,  NW2[l], 64};
    }
    conv_weights<<<dim3(48, 8), 256, 0, stream>>>(pack);

    const int egrid = (E + 63) / 64;
    const int ngrid = (N + 63) / 64;
    const int agrid = (N + 15) / 16;

    if (sortedOK) {
        // ---- CSR build (once) ----
        (void)hipMemsetAsync(counts, 0, (size_t)N * sizeof(int), stream);
        hist_kernel<<<(E + 255) / 256, 256, 0, stream>>>(dstI, counts, E);
        scan_kernel<<<1, 1024, 0, stream>>>(counts, row_ptr, N, E);
        scatter_kernel<<<(E + 255) / 256, 256, 0, stream>>>(
            srcI, dstI, counts, csr_eid, srcS, dstS, E);

        // layer 1: ea0 fp32 gather -> ea_mid f16 sorted
        gnn_edge_sorted<false, false><<<egrid, 256, 0, stream>>>(
            x0, ea0, eaH, nullptr, csr_eid, srcS, dstS,
            EW1[0], eb1, EW2[0], eb2, E);
        agg_seg<<<agrid, 256, 0, stream>>>(eaH, row_ptr, agg, N);
        gnn_node_mfma<<<ngrid, 256, 0, stream>>>(
            x0, agg, outX, NW1[0], nb1, NW2[0], nb2, N);

        // layer 2: ea_mid f16 sequential -> ea_mid (in-place) + outE scatter
        gnn_edge_sorted<true, true><<<egrid, 256, 0, stream>>>(
            outX, nullptr, eaH, outE, csr_eid, srcS, dstS,
            EW1[1], eb1 + H, EW2[1], eb2 + H, E);
        agg_seg<<<agrid, 256, 0, stream>>>(eaH, row_ptr, agg, N);
        gnn_node_mfma<<<ngrid, 256, 0, stream>>>(
            outX, agg, outX, NW1[1], nb1 + H, NW2[1], nb2 + H, N);
    } else {
        // fallback: R10 unsorted path with atomics
        for (int l = 0; l < 2; ++l) {
            const float* xin = (l == 0) ? x0 : outX;
            (void)hipMemsetAsync(agg, 0, aggBytes, stream);
            if (f16OK) {
                if (l == 0)
                    gnn_edge_mfma<false, true><<<egrid, 256, 0, stream>>>(
                        xin, ea0, nullptr, nullptr, eaH, srcI, dstI,
                        EW1[l], eb1 + l * H, EW2[l], eb2 + l * H, agg, E);
                else
                    gnn_edge_mfma<true, false><<<egrid, 256, 0, stream>>>(
                        xin, nullptr, eaH, outE, nullptr, srcI, dstI,
                        EW1[l], eb1 + l * H, EW2[l], eb2 + l * H, agg, E);
            } else {
                const float* eain = (l == 0) ? ea0 : outE;
                gnn_edge_mfma<false, false><<<egrid, 256, 0, stream>>>(
                    xin, eain, nullptr, outE, nullptr, srcI, dstI,
                    EW1[l], eb1 + l * H, EW2[l], eb2 + l * H, agg, E);
            }
            gnn_node_mfma<<<ngrid, 256, 0, stream>>>(
                xin, agg, outX,
                NW1[l], nb1 + l * H, NW2[l], nb2 + l * H, N);
        }
    }
}

// Round 12
// 558.468 us; speedup vs baseline: 1.0599x; 1.0599x over previous
//
#include <hip/hip_runtime.h>

typedef __attribute__((ext_vector_type(8))) _Float16 f16x8;
typedef __attribute__((ext_vector_type(4))) _Float16 f16x4;
typedef __attribute__((ext_vector_type(4))) float f32x4;

#define PWS 72   // LDS tile pitch in halfs: 144B rows, 16B-aligned chunks

__device__ __forceinline__ float silu_f(float v) {
    return v * (1.0f / (1.0f + __expf(-v)));
}

// bijective XCD-aware block swizzle (m204 variant; identity for tiny grids)
__device__ __forceinline__ int xcd_swz(int bid, int nwg) {
    if (nwg < 16) return bid;
    int q = nwg >> 3, r = nwg & 7;
    int x = bid & 7, i = bid >> 3;
    int basex = (x < r) ? x * (q + 1) : r * (q + 1) + (x - r) * q;
    return basex + i;
}

// ---------------------------------------------------------------------------
// Weight pre-conversion: fp32 [K][64] -> f16 in B-fragment order.
// ---------------------------------------------------------------------------
struct WDesc { const float* W; _Float16* out; int K; };
struct WPack { WDesc d[8]; };

__global__ __launch_bounds__(256) void conv_weights(WPack p) {
    WDesc wd = p.d[blockIdx.y];
    int total = wd.K * 64;
    int i = blockIdx.x * 256 + threadIdx.x;
    if (i >= total) return;
    int j  = i & 7;
    int l  = (i >> 3) & 63;
    int tn = i >> 9;                 // t*4 + nf
    int t  = tn >> 2, nf = tn & 3;
    int k  = t * 32 + (l >> 4) * 8 + j;
    int c  = nf * 16 + (l & 15);
    wd.out[i] = (_Float16)wd.W[k * 64 + c];   // RNE
}

// ---------------------------------------------------------------------------
// CSR build: histogram -> single-block scan -> scatter (packed int4 records).
// ---------------------------------------------------------------------------
__global__ __launch_bounds__(256) void hist_kernel(const int* __restrict__ dst,
                                                   int* __restrict__ counts, int E) {
    int e = blockIdx.x * 256 + threadIdx.x;
    if (e < E) atomicAdd(&counts[dst[e]], 1);
}

__global__ __launch_bounds__(1024) void scan_kernel(int* __restrict__ counts,
                                                    int* __restrict__ row_ptr,
                                                    int N, int E) {
    __shared__ int part[1024];
    int t = threadIdx.x;
    int per = (N + 1023) >> 10;
    int s = t * per, en = min(s + per, N);
    int sum = 0;
    for (int i = s; i < en; ++i) sum += counts[i];
    part[t] = sum;
    __syncthreads();
    for (int off = 1; off < 1024; off <<= 1) {
        int v = (t >= off) ? part[t - off] : 0;
        __syncthreads();
        part[t] += v;
        __syncthreads();
    }
    int run = (t == 0) ? 0 : part[t - 1];
    for (int i = s; i < en; ++i) {
        int c = counts[i];
        row_ptr[i] = run;
        counts[i] = run;        // becomes the scatter cursor
        run += c;
    }
    if (t == 1023) row_ptr[N] = E;
}

__global__ __launch_bounds__(256) void scatter_kernel(
    const int* __restrict__ src, const int* __restrict__ dst,
    int* __restrict__ cursor, int4* __restrict__ pk, int E) {
    int e = blockIdx.x * 256 + threadIdx.x;
    if (e < E) {
        int d = dst[e];
        int pos = atomicAdd(&cursor[d], 1);
        pk[pos] = make_int4(e, src[e], d, 0);   // one 16B record
    }
}

// ---------------------------------------------------------------------------
// Sorted edge kernel: 4 independent waves/block, wave owns 16 sorted
// positions. No atomics, no barriers. IN16: ea from sorted f16 ea_mid
// (sequential); else gather fp32 ea0 via pk.x. Always writes sorted f16
// ea_mid (in-place safe). FINAL: additionally scatter fp32 result to
// ea_out[eid].
// ---------------------------------------------------------------------------
template <bool IN16, bool FINAL>
__global__ __launch_bounds__(256, 8) void gnn_edge_sorted(
    const float* __restrict__ x,
    const float* __restrict__ ea0,
    _Float16* __restrict__ ea_mid,
    float* __restrict__ ea_out,
    const int4* __restrict__ pk,
    const _Float16* __restrict__ w1f,
    const float* __restrict__ b1,
    const _Float16* __restrict__ w2f,
    const float* __restrict__ b2,
    int E, int nwg)
{
    __shared__ __align__(16) _Float16 sA[64][PWS];

    const int t    = threadIdx.x;
    const int lane = t & 63;
    const int w    = t >> 6;
    const int col  = lane & 15;
    const int g    = lane >> 4;
    const int ko   = g * 8;
    const int bid  = xcd_swz(blockIdx.x, nwg);
    const long base = (long)bid * 64;

    // this lane's own position -> eid for the FINAL scatter epilogue
    long p0 = base + w * 16 + col;
    if (p0 >= E) p0 = E - 1;
    int ei0 = 0;
    if constexpr (FINAL) ei0 = pk[p0].x;

    // ---- upfront loads: rows it*4+g of the wave tile, cols col*4..+4 ----
    f16x4  ea16v[4];
    float4 ea4[4];
    float4 sx4[4], dx4[4];
#pragma unroll
    for (int it = 0; it < 4; ++it) {
        long p = base + w * 16 + it * 4 + g;
        if (p >= E) p = E - 1;
        int4 rec = pk[p];
        if constexpr (IN16) {
            ea16v[it] = *(const f16x4*)(ea_mid + p * 64 + col * 4);
        } else {
            ea4[it] = *(const float4*)(ea0 + (long)rec.x * 64 + col * 4);
        }
        sx4[it] = *(const float4*)(x + (long)rec.y * 64 + col * 4);
        dx4[it] = *(const float4*)(x + (long)rec.z * 64 + col * 4);
    }

    f32x4 acc[4];
#pragma unroll
    for (int nf = 0; nf < 4; ++nf) {
        float bv = b1[nf * 16 + col];
        acc[nf] = (f32x4){bv, bv, bv, bv};
    }

    const int arow = w * 16 + col;

#define MFMA_L1(s3)                                                             \
    _Pragma("unroll")                                                           \
    for (int tt = 0; tt < 2; ++tt) {                                            \
        int k0 = tt * 32 + ko;                                                  \
        f16x8 af = *(const f16x8*)&sA[arow][k0];                                \
        int tg = (s3) * 2 + tt;                                                 \
        _Pragma("unroll")                                                       \
        for (int nf = 0; nf < 4; ++nf) {                                        \
            f16x8 bf = *(const f16x8*)(w1f + (size_t)((tg*4+nf)*64+lane)*8);    \
            acc[nf] = __builtin_amdgcn_mfma_f32_16x16x32_f16(af, bf, acc[nf], 0, 0, 0); \
        }                                                                       \
    }

    // ---- segment 0: edge_attr (k 0..63) ----
#pragma unroll
    for (int it = 0; it < 4; ++it) {
        int rg = w * 16 + it * 4 + g;
        f16x4 hv;
        if constexpr (IN16) {
            hv = ea16v[it];
        } else {
            hv[0] = (_Float16)ea4[it].x; hv[1] = (_Float16)ea4[it].y;
            hv[2] = (_Float16)ea4[it].z; hv[3] = (_Float16)ea4[it].w;
        }
        *(f16x4*)&sA[rg][col * 4] = hv;
    }
    MFMA_L1(0)

    // ---- segment 1: x[src] (k 64..127) ----
#pragma unroll
    for (int it = 0; it < 4; ++it) {
        int rg = w * 16 + it * 4 + g;
        f16x4 hv;
        hv[0] = (_Float16)sx4[it].x; hv[1] = (_Float16)sx4[it].y;
        hv[2] = (_Float16)sx4[it].z; hv[3] = (_Float16)sx4[it].w;
        *(f16x4*)&sA[rg][col * 4] = hv;
    }
    MFMA_L1(1)

    // ---- segment 2: x[dst] (k 128..191) ----
#pragma unroll
    for (int it = 0; it < 4; ++it) {
        int rg = w * 16 + it * 4 + g;
        f16x4 hv;
        hv[0] = (_Float16)dx4[it].x; hv[1] = (_Float16)dx4[it].y;
        hv[2] = (_Float16)dx4[it].z; hv[3] = (_Float16)dx4[it].w;
        *(f16x4*)&sA[rg][col * 4] = hv;
    }
    MFMA_L1(2)
#undef MFMA_L1

    // ---- silu -> h staged into the wave's own 16 LDS rows (C-frag layout) ----
#pragma unroll
    for (int nf = 0; nf < 4; ++nf)
#pragma unroll
        for (int rg = 0; rg < 4; ++rg) {
            int row = w * 16 + g * 4 + rg;
            sA[row][nf * 16 + col] = (_Float16)silu_f(acc[nf][rg]);
        }

    // ---- layer-2 GEMM (K=64) ----
    f32x4 out[4];
#pragma unroll
    for (int nf = 0; nf < 4; ++nf) {
        float bv = b2[nf * 16 + col];
        out[nf] = (f32x4){bv, bv, bv, bv};
    }
#pragma unroll
    for (int tt = 0; tt < 2; ++tt) {
        int k0 = tt * 32 + ko;
        f16x8 af = *(const f16x8*)&sA[arow][k0];
#pragma unroll
        for (int nf = 0; nf < 4; ++nf) {
            f16x8 bf = *(const f16x8*)(w2f + (size_t)((tt * 4 + nf) * 64 + lane) * 8);
            out[nf] = __builtin_amdgcn_mfma_f32_16x16x32_f16(af, bf, out[nf], 0, 0, 0);
        }
    }

    // ---- epilogue: sequential f16 ea_mid write (+ FINAL fp32 scatter) ----
    const int rbase = w * 16 + g * 4;
#pragma unroll
    for (int rg = 0; rg < 4; ++rg) {
        long p = base + rbase + rg;
        if (p < E) {
#pragma unroll
            for (int nf = 0; nf < 4; ++nf)
                ea_mid[p * 64 + nf * 16 + col] = (_Float16)out[nf][rg];
            if constexpr (FINAL) {
                int eid = __shfl(ei0, g * 4 + rg);
                float* op = ea_out + (long)eid * 64;
#pragma unroll
                for (int nf = 0; nf < 4; ++nf)
                    op[nf * 16 + col] = out[nf][rg];
            }
        }
    }
}

// ---------------------------------------------------------------------------
// Fused node kernel: per-lane segment-sum of sorted f16 ea_mid replaces the
// separate agg pass (segments of a wave's 16 nodes are contiguous in ea_mid
// and L3-resident). x A-frags direct; LDS only for h transpose.
// ---------------------------------------------------------------------------
__global__ __launch_bounds__(256, 4) void gnn_node_fused(
    const float* __restrict__ x_in,
    const _Float16* __restrict__ eaH,
    const int* __restrict__ row_ptr,
    float* __restrict__ x_out,
    const _Float16* __restrict__ w1f,
    const float* __restrict__ b1,
    const _Float16* __restrict__ w2f,
    const float* __restrict__ b2, int N, int nwg)
{
    __shared__ __align__(16) _Float16 sA[64][PWS];

    const int t    = threadIdx.x;
    const int lane = t & 63;
    const int w    = t >> 6;
    const int col  = lane & 15;
    const int g    = lane >> 4;
    const int ko   = g * 8;
    const int bid  = xcd_swz(blockIdx.x, nwg);
    const long base = (long)bid * 64;

    long nr = base + w * 16 + col;
    if (nr >= N) nr = N - 1;
    const float* px = x_in + nr * 64 + ko;

    float4 v0 = *(const float4*)(px);
    float4 v1 = *(const float4*)(px + 4);
    float4 v2 = *(const float4*)(px + 32);
    float4 v3 = *(const float4*)(px + 36);

    // ---- segment-sum of eaH over this node's sorted range (both k-chunks) ----
    int pe0 = row_ptr[nr], pe1 = row_ptr[nr + 1];
    float s0[8], s1[8];
#pragma unroll
    for (int j = 0; j < 8; ++j) { s0[j] = 0.f; s1[j] = 0.f; }
    for (int p = pe0; p < pe1; ++p) {
        f16x8 a = *(const f16x8*)(eaH + (long)p * 64 + ko);
        f16x8 b = *(const f16x8*)(eaH + (long)p * 64 + 32 + ko);
#pragma unroll
        for (int j = 0; j < 8; ++j) { s0[j] += (float)a[j]; s1[j] += (float)b[j]; }
    }

    f32x4 acc[4];
#pragma unroll
    for (int nf = 0; nf < 4; ++nf) {
        float bv = b1[nf * 16 + col];
        acc[nf] = (f32x4){bv, bv, bv, bv};
    }

#define QTRV(m, A, B)                                                           \
    {                                                                           \
        f16x8 af;                                                               \
        af[0] = (_Float16)A.x; af[1] = (_Float16)A.y;                           \
        af[2] = (_Float16)A.z; af[3] = (_Float16)A.w;                           \
        af[4] = (_Float16)B.x; af[5] = (_Float16)B.y;                           \
        af[6] = (_Float16)B.z; af[7] = (_Float16)B.w;                           \
        _Pragma("unroll")                                                       \
        for (int nf = 0; nf < 4; ++nf) {                                        \
            f16x8 bf = *(const f16x8*)(w1f + (size_t)(((m)*4+nf)*64+lane)*8);   \
            acc[nf] = __builtin_amdgcn_mfma_f32_16x16x32_f16(af, bf, acc[nf], 0, 0, 0); \
        }                                                                       \
    }
#define QTRS(m, S)                                                              \
    {                                                                           \
        f16x8 af;                                                               \
        _Pragma("unroll")                                                       \
        for (int j = 0; j < 8; ++j) af[j] = (_Float16)S[j];                     \
        _Pragma("unroll")                                                       \
        for (int nf = 0; nf < 4; ++nf) {                                        \
            f16x8 bf = *(const f16x8*)(w1f + (size_t)(((m)*4+nf)*64+lane)*8);   \
            acc[nf] = __builtin_amdgcn_mfma_f32_16x16x32_f16(af, bf, acc[nf], 0, 0, 0); \
        }                                                                       \
    }
    QTRV(0, v0, v1)  QTRV(1, v2, v3)   // x    (k 0..63)
    QTRS(2, s0)      QTRS(3, s1)       // agg  (k 64..127)
#undef QTRV
#undef QTRS

#pragma unroll
    for (int nf = 0; nf < 4; ++nf)
#pragma unroll
        for (int rg = 0; rg < 4; ++rg) {
            int row = w * 16 + g * 4 + rg;
            sA[row][nf * 16 + col] = (_Float16)silu_f(acc[nf][rg]);
        }

    f32x4 out[4];
#pragma unroll
    for (int nf = 0; nf < 4; ++nf) {
        float bv = b2[nf * 16 + col];
        out[nf] = (f32x4){bv, bv, bv, bv};
    }
    const int arow = w * 16 + col;
#pragma unroll
    for (int tt = 0; tt < 2; ++tt) {
        int k0 = tt * 32 + ko;
        f16x8 af = *(const f16x8*)&sA[arow][k0];
#pragma unroll
        for (int nf = 0; nf < 4; ++nf) {
            f16x8 bf = *(const f16x8*)(w2f + (size_t)((tt * 4 + nf) * 64 + lane) * 8);
            out[nf] = __builtin_amdgcn_mfma_f32_16x16x32_f16(af, bf, out[nf], 0, 0, 0);
        }
    }

    const int rbase = w * 16 + g * 4;
#pragma unroll
    for (int rg = 0; rg < 4; ++rg) {
        long row = base + rbase + rg;
        if (row < N) {
            float* op = x_out + row * 64;
#pragma unroll
            for (int nf = 0; nf < 4; ++nf)
                op[nf * 16 + col] = out[nf][rg];
        }
    }
}

// ---------------------------------------------------------------------------
// Fallback unsorted edge kernel (atomics) + plain node kernel — used only if
// workspace is too small for the sorted pipeline.
// ---------------------------------------------------------------------------
__global__ __launch_bounds__(256, 8) void gnn_edge_mfma(
    const float* __restrict__ x,
    const float* __restrict__ ea_in,
    float* __restrict__ ea_out,
    const int* __restrict__ src_idx,
    const int* __restrict__ dst_idx,
    const _Float16* __restrict__ w1f,
    const float* __restrict__ b1,
    const _Float16* __restrict__ w2f,
    const float* __restrict__ b2,
    float* __restrict__ agg,
    int E)
{
    __shared__ __align__(16) _Float16 sA[64][PWS];

    const int t    = threadIdx.x;
    const int lane = t & 63;
    const int w    = t >> 6;
    const int col  = lane & 15;
    const int g    = lane >> 4;
    const int ko   = g * 8;
    const long base = (long)blockIdx.x * 64;

    long er0 = base + w * 16 + col;
    if (er0 >= E) er0 = E - 1;
    const int di = dst_idx[er0];

    float4 ea4[4], sx4[4], dx4[4];
#pragma unroll
    for (int it = 0; it < 4; ++it) {
        long er = base + w * 16 + it * 4 + g;
        if (er >= E) er = E - 1;
        ea4[it] = *(const float4*)(ea_in + er * 64 + col * 4);
        sx4[it] = *(const float4*)(x + (long)src_idx[er] * 64 + col * 4);
        dx4[it] = *(const float4*)(x + (long)dst_idx[er] * 64 + col * 4);
    }

    f32x4 acc[4];
#pragma unroll
    for (int nf = 0; nf < 4; ++nf) {
        float bv = b1[nf * 16 + col];
        acc[nf] = (f32x4){bv, bv, bv, bv};
    }
    const int arow = w * 16 + col;

#define MFMA_L1(s3)                                                             \
    _Pragma("unroll")                                                           \
    for (int tt = 0; tt < 2; ++tt) {                                            \
        int k0 = tt * 32 + ko;                                                  \
        f16x8 af = *(const f16x8*)&sA[arow][k0];                                \
        int tg = (s3) * 2 + tt;                                                 \
        _Pragma("unroll")                                                       \
        for (int nf = 0; nf < 4; ++nf) {                                        \
            f16x8 bf = *(const f16x8*)(w1f + (size_t)((tg*4+nf)*64+lane)*8);    \
            acc[nf] = __builtin_amdgcn_mfma_f32_16x16x32_f16(af, bf, acc[nf], 0, 0, 0); \
        }                                                                       \
    }

#pragma unroll
    for (int it = 0; it < 4; ++it) {
        int rg = w * 16 + it * 4 + g;
        f16x4 hv;
        hv[0] = (_Float16)ea4[it].x; hv[1] = (_Float16)ea4[it].y;
        hv[2] = (_Float16)ea4[it].z; hv[3] = (_Float16)ea4[it].w;
        *(f16x4*)&sA[rg][col * 4] = hv;
    }
    MFMA_L1(0)
#pragma unroll
    for (int it = 0; it < 4; ++it) {
        int rg = w * 16 + it * 4 + g;
        f16x4 hv;
        hv[0] = (_Float16)sx4[it].x; hv[1] = (_Float16)sx4[it].y;
        hv[2] = (_Float16)sx4[it].z; hv[3] = (_Float16)sx4[it].w;
        *(f16x4*)&sA[rg][col * 4] = hv;
    }
    MFMA_L1(1)
#pragma unroll
    for (int it = 0; it < 4; ++it) {
        int rg = w * 16 + it * 4 + g;
        f16x4 hv;
        hv[0] = (_Float16)dx4[it].x; hv[1] = (_Float16)dx4[it].y;
        hv[2] = (_Float16)dx4[it].z; hv[3] = (_Float16)dx4[it].w;
        *(f16x4*)&sA[rg][col * 4] = hv;
    }
    MFMA_L1(2)
#undef MFMA_L1

#pragma unroll
    for (int nf = 0; nf < 4; ++nf)
#pragma unroll
        for (int rg = 0; rg < 4; ++rg) {
            int row = w * 16 + g * 4 + rg;
            sA[row][nf * 16 + col] = (_Float16)silu_f(acc[nf][rg]);
        }

    f32x4 out[4];
#pragma unroll
    for (int nf = 0; nf < 4; ++nf) {
        float bv = b2[nf * 16 + col];
        out[nf] = (f32x4){bv, bv, bv, bv};
    }
#pragma unroll
    for (int tt = 0; tt < 2; ++tt) {
        int k0 = tt * 32 + ko;
        f16x8 af = *(const f16x8*)&sA[arow][k0];
#pragma unroll
        for (int nf = 0; nf < 4; ++nf) {
            f16x8 bf = *(const f16x8*)(w2f + (size_t)((tt * 4 + nf) * 64 + lane) * 8);
            out[nf] = __builtin_amdgcn_mfma_f32_16x16x32_f16(af, bf, out[nf], 0, 0, 0);
        }
    }

    const int rbase = w * 16 + g * 4;
#pragma unroll
    for (int rg = 0; rg < 4; ++rg) {
        long row = base + rbase + rg;
        if (row < E) {
            int drow = __shfl(di, g * 4 + rg);
            float* ap = agg + (long)drow * 64;
#pragma unroll
            for (int nf = 0; nf < 4; ++nf) {
                ea_out[row * 64 + nf * 16 + col] = out[nf][rg];
                atomicAdd(&ap[nf * 16 + col], out[nf][rg]);
            }
        }
    }
}

__global__ __launch_bounds__(256, 8) void gnn_node_mfma(
    const float* __restrict__ x_in,
    const float* __restrict__ aggp,
    float* __restrict__ x_out,
    const _Float16* __restrict__ w1f,
    const float* __restrict__ b1,
    const _Float16* __restrict__ w2f,
    const float* __restrict__ b2, int N)
{
    __shared__ __align__(16) _Float16 sA[64][PWS];

    const int t    = threadIdx.x;
    const int lane = t & 63;
    const int w    = t >> 6;
    const int col  = lane & 15;
    const int g    = lane >> 4;
    const int ko   = g * 8;
    const long base = (long)blockIdx.x * 64;

    long nr = base + w * 16 + col;
    if (nr >= N) nr = N - 1;
    const float* px = x_in + nr * 64 + ko;
    const float* pa = aggp + nr * 64 + ko;

    float4 v0 = *(const float4*)(px);
    float4 v1 = *(const float4*)(px + 4);
    float4 v2 = *(const float4*)(px + 32);
    float4 v3 = *(const float4*)(px + 36);
    float4 v4 = *(const float4*)(pa);
    float4 v5 = *(const float4*)(pa + 4);
    float4 v6 = *(const float4*)(pa + 32);
    float4 v7 = *(const float4*)(pa + 36);

    f32x4 acc[4];
#pragma unroll
    for (int nf = 0; nf < 4; ++nf) {
        float bv = b1[nf * 16 + col];
        acc[nf] = (f32x4){bv, bv, bv, bv};
    }

#define QTR(m, A, B)                                                            \
    {                                                                           \
        f16x8 af;                                                               \
        af[0] = (_Float16)A.x; af[1] = (_Float16)A.y;                           \
        af[2] = (_Float16)A.z; af[3] = (_Float16)A.w;                           \
        af[4] = (_Float16)B.x; af[5] = (_Float16)B.y;                           \
        af[6] = (_Float16)B.z; af[7] = (_Float16)B.w;                           \
        _Pragma("unroll")                                                       \
        for (int nf = 0; nf < 4; ++nf) {                                        \
            f16x8 bf = *(const f16x8*)(w1f + (size_t)(((m)*4+nf)*64+lane)*8);   \
            acc[nf] = __builtin_amdgcn_mfma_f32_16x16x32_f16(af, bf, acc[nf], 0, 0, 0); \
        }                                                                       \
    }
    QTR(0, v0, v1)  QTR(1, v2, v3)
    QTR(2, v4, v5)  QTR(3, v6, v7)
#undef QTR

#pragma unroll
    for (int nf = 0; nf < 4; ++nf)
#pragma unroll
        for (int rg = 0; rg < 4; ++rg) {
            int row = w * 16 + g * 4 + rg;
            sA[row][nf * 16 + col] = (_Float16)silu_f(acc[nf][rg]);
        }

    f32x4 out[4];
#pragma unroll
    for (int nf = 0; nf < 4; ++nf) {
        float bv = b2[nf * 16 + col];
        out[nf] = (f32x4){bv, bv, bv, bv};
    }
    const int arow = w * 16 + col;
#pragma unroll
    for (int tt = 0; tt < 2; ++tt) {
        int k0 = tt * 32 + ko;
        f16x8 af = *(const f16x8*)&sA[arow][k0];
#pragma unroll
        for (int nf = 0; nf < 4; ++nf) {
            f16x8 bf = *(const f16x8*)(w2f + (size_t)((tt * 4 + nf) * 64 + lane) * 8);
            out[nf] = __builtin_amdgcn_mfma_f32_16x16x32_f16(af, bf, out[nf], 0, 0, 0);
        }
    }

    const int rbase = w * 16 + g * 4;
#pragma unroll
    for (int rg = 0; rg < 4; ++rg) {
        long row = base + rbase + rg;
        if (row < N) {
            float* op = x_out + row * 64;
#pragma unroll
            for (int nf = 0; nf < 4; ++nf)
                op[nf * 16 + col] = out[nf][rg];
        }
    }
}

extern "C" void kernel_launch(void* const* d_in, const int* in_sizes, int n_in,
                              void* d_out, int out_size, void* d_ws, size_t ws_size,
                              hipStream_t stream) {
    const int H = 64;
    const int N = in_sizes[0] / H;   // 50000
    const int E = in_sizes[1] / H;   // 800000

    const float* x0  = (const float*)d_in[0];
    const float* ea0 = (const float*)d_in[1];
    const int*   ei  = (const int*)d_in[2];
    const float* ew1 = (const float*)d_in[3];
    const float* eb1 = (const float*)d_in[4];
    const float* ew2 = (const float*)d_in[5];
    const float* eb2 = (const float*)d_in[6];
    const float* nw1 = (const float*)d_in[7];
    const float* nb1 = (const float*)d_in[8];
    const float* nw2 = (const float*)d_in[9];
    const float* nb2 = (const float*)d_in[10];

    float* outX = (float*)d_out;                 // [N, H]
    float* outE = outX + (size_t)N * H;          // [E, H]

    // workspace carve: agg(fallback) | weights | eaH f16 | counts | row_ptr | pk
    const size_t aggBytes = (size_t)N * H * sizeof(float);
    const size_t wElems   = 2 * ((size_t)(192 + 64 + 128 + 64) * 64);
    const size_t eaHBytes = (size_t)E * H * sizeof(_Float16);

    float* agg      = (float*)d_ws;
    _Float16* wbase = (_Float16*)((char*)d_ws + aggBytes);
    char* eaH_raw   = (char*)(wbase + wElems);
    eaH_raw = (char*)(((uintptr_t)eaH_raw + 15) & ~(uintptr_t)15);
    _Float16* eaH   = (_Float16*)eaH_raw;
    int* counts     = (int*)(((uintptr_t)((char*)eaH + eaHBytes) + 15) & ~(uintptr_t)15);
    int* row_ptr    = counts + N;
    int4* pk        = (int4*)(((uintptr_t)(row_ptr + N + 1) + 15) & ~(uintptr_t)15);

    const bool sortedOK = ((char*)(pk + E)) <= ((char*)d_ws + ws_size);

    const int* srcI = ei;
    const int* dstI = ei + E;

    WPack pack;
    size_t off = 0;
    _Float16* EW1[2]; _Float16* EW2[2]; _Float16* NW1[2]; _Float16* NW2[2];
    for (int l = 0; l < 2; ++l) {
        EW1[l] = wbase + off; off += 192 * 64;
        EW2[l] = wbase + off; off += 64 * 64;
        NW1[l] = wbase + off; off += 128 * 64;
        NW2[l] = wbase + off; off += 64 * 64;
        pack.d[l * 4 + 0] = {ew1 + (size_t)l * 192 * 64, EW1[l], 192};
        pack.d[l * 4 + 1] = {ew2 + (size_t)l * 64 * 64,  EW2[l], 64};
        pack.d[l * 4 + 2] = {nw1 + (size_t)l * 128 * 64, NW1[l], 128};
        pack.d[l * 4 + 3] = {nw2 + (size_t)l * 64 * 64,  NW2[l], 64};
    }
    conv_weights<<<dim3(48, 8), 256, 0, stream>>>(pack);

    const int egrid = (E + 63) / 64;
    const int ngrid = (N + 63) / 64;

    if (sortedOK) {
        // ---- CSR build (once) ----
        (void)hipMemsetAsync(counts, 0, (size_t)N * sizeof(int), stream);
        hist_kernel<<<(E + 255) / 256, 256, 0, stream>>>(dstI, counts, E);
        scan_kernel<<<1, 1024, 0, stream>>>(counts, row_ptr, N, E);
        scatter_kernel<<<(E + 255) / 256, 256, 0, stream>>>(
            srcI, dstI, counts, pk, E);

        // layer 1
        gnn_edge_sorted<false, false><<<egrid, 256, 0, stream>>>(
            x0, ea0, eaH, nullptr, pk,
            EW1[0], eb1, EW2[0], eb2, E, egrid);
        gnn_node_fused<<<ngrid, 256, 0, stream>>>(
            x0, eaH, row_ptr, outX, NW1[0], nb1, NW2[0], nb2, N, ngrid);

        // layer 2 (ea_mid in-place + final outE scatter)
        gnn_edge_sorted<true, true><<<egrid, 256, 0, stream>>>(
            outX, nullptr, eaH, outE, pk,
            EW1[1], eb1 + H, EW2[1], eb2 + H, E, egrid);
        gnn_node_fused<<<ngrid, 256, 0, stream>>>(
            outX, eaH, row_ptr, outX, NW1[1], nb1 + H, NW2[1], nb2 + H, N, ngrid);
    } else {
        // fallback: unsorted path with atomics
        for (int l = 0; l < 2; ++l) {
            const float* xin  = (l == 0) ? x0  : outX;
            const float* eain = (l == 0) ? ea0 : outE;
            (void)hipMemsetAsync(agg, 0, aggBytes, stream);
            gnn_edge_mfma<<<egrid, 256, 0, stream>>>(
                xin, eain, outE, srcI, dstI,
                EW1[l], eb1 + l * H, EW2[l], eb2 + l * H, agg, E);
            gnn_node_mfma<<<ngrid, 256, 0, stream>>>(
                xin, agg, outX,
                NW1[l], nb1 + l * H, NW2[l], nb2 + l * H, N);
        }
    }
}